// Round 1
// baseline (237.112 us; speedup 1.0000x reference)
//
#include <hip/hip_runtime.h>
#include <math.h>

typedef float vf4 __attribute__((ext_vector_type(4)));

// ======================================================================
// CG setup kernel: ports the reference's real-spherical-harmonic CG
// construction (complex CG -> q-matrix change of basis -> real part ->
// Frobenius-normalize -> * alpha) in fp64. Runs every launch (~2us),
// writes fused tables to d_ws: path p at ws[p*128 + (i*D2+j)*D3 + k].
// ======================================================================
struct cpx { double re, im; };
__device__ __forceinline__ cpx cmul(cpx a, cpx b){
  return cpx{ a.re*b.re - a.im*b.im, a.re*b.im + a.im*b.re };
}

__device__ double dfact(int n){ double r = 1.0; for (int i = 2; i <= n; i++) r *= (double)i; return r; }

__device__ double cgcoef(int j1,int m1,int j2,int m2,int j3,int m3){
  if (m1 + m2 != m3) return 0.0;
  double pref = sqrt((double)(2*j3+1) * dfact(j3+j1-j2) * dfact(j3-j1+j2)
                     * dfact(j1+j2-j3) / dfact(j1+j2+j3+1));
  pref *= sqrt(dfact(j3+m3)*dfact(j3-m3)*dfact(j1-m1)*dfact(j1+m1)*dfact(j2-m2)*dfact(j2+m2));
  double s = 0.0;
  for (int k = 0; k <= j1+j2-j3; k++){
    int e1 = j1+j2-j3-k, e2 = j1-m1-k, e3 = j2+m2-k, e4 = j3-j2+m1+k, e5 = j3-j1-m2+k;
    if (e1 < 0 || e2 < 0 || e3 < 0 || e4 < 0 || e5 < 0) continue;
    double prod = dfact(k)*dfact(e1)*dfact(e2)*dfact(e3)*dfact(e4)*dfact(e5);
    s += ((k & 1) ? -1.0 : 1.0) / prod;
  }
  return pref * s;
}

// Path order must match the reference PATHS enumeration (l1-major, l2, l3):
__device__ const int PL1[11] = {0,0,0,1,1,1,1,2,2,2,2};
__device__ const int PL2[11] = {0,1,2,0,1,1,2,0,1,2,2};
__device__ const int PL3[11] = {0,1,2,1,0,2,1,2,1,0,2};
__device__ const int EOFF[12] = {0,1,10,35,44,53,98,143,168,213,238,363};
__device__ const int QO[3]   = {0,1,10};
__device__ const int NOUT3[3] = {3,4,4};

__global__ void cg_setup_kernel(float* __restrict__ ws)
{
  __shared__ cpx    Q[35];     // q matrices for l=0,1,2 (1+9+25)
  __shared__ double CS[363];   // complex-basis CG (su2), packed per EOFF
  __shared__ double CR[363];   // real part of transformed CG
  __shared__ double NRM[11];
  const int t = threadIdx.x;

  if (t == 0) {
    const double is2 = 0.70710678118654752440;
    for (int l = 0; l < 3; l++){
      int d = 2*l + 1;
      cpx* q = &Q[QO[l]];
      for (int i = 0; i < d*d; i++) q[i] = cpx{0.0, 0.0};
      for (int m = -l; m < 0; m++){
        q[(l+m)*d + (l-m)] = cpx{ is2, 0.0 };   // col l+|m|
        q[(l+m)*d + (l+m)] = cpx{ 0.0, -is2 };  // col l-|m|
      }
      q[l*d + l] = cpx{1.0, 0.0};
      for (int m = 1; m <= l; m++){
        double sgn = (m & 1) ? -1.0 : 1.0;
        q[(l+m)*d + (l+m)] = cpx{ sgn*is2, 0.0 };
        q[(l+m)*d + (l-m)] = cpx{ 0.0, sgn*is2 };
      }
      // multiply by (-i)^l
      for (int i = 0; i < d*d; i++){
        cpx v = q[i];
        if (l == 1)      q[i] = cpx{  v.im, -v.re };
        else if (l == 2) q[i] = cpx{ -v.re, -v.im };
      }
    }
  }
  __syncthreads();

  int p = 0, loc = 0, l1 = 0, l2 = 0, l3 = 0, d1 = 1, d2 = 1, d3 = 1;
  if (t < 363) {
    while (p < 10 && t >= EOFF[p+1]) p++;
    loc = t - EOFF[p];
    l1 = PL1[p]; l2 = PL2[p]; l3 = PL3[p];
    d1 = 2*l1+1; d2 = 2*l2+1; d3 = 2*l3+1;
  }

  if (t < 363) {
    int i = loc/(d2*d3), rem = loc%(d2*d3), k = rem/d3, m = rem%d3;
    CS[t] = cgcoef(l1, i-l1, l2, k-l2, l3, m-l3);
  }
  __syncthreads();

  if (t < 363) {
    int j = loc/(d2*d3), rem = loc%(d2*d3), lc = rem/d3, n = rem%d3;
    cpx acc = {0.0, 0.0};
    for (int i = 0; i < d1; i++){
      cpx a = Q[QO[l1] + i*d1 + j];
      if (a.re == 0.0 && a.im == 0.0) continue;
      for (int k = 0; k < d2; k++){
        cpx b = Q[QO[l2] + k*d2 + lc];
        if (b.re == 0.0 && b.im == 0.0) continue;
        cpx ab = cmul(a, b);
        for (int m = 0; m < d3; m++){
          double cs = CS[EOFF[p] + (i*d2+k)*d3 + m];
          if (cs == 0.0) continue;
          cpx qc = Q[QO[l3] + m*d3 + n];
          cpx cj = { qc.re, -qc.im };       // conj(q3)
          cpx tt = cmul(ab, cj);
          acc.re += tt.re * cs;
          acc.im += tt.im * cs;
        }
      }
    }
    CR[t] = acc.re;
  }
  __syncthreads();

  if (t < 11) {
    double s = 0.0;
    for (int i = EOFF[t]; i < EOFF[t+1]; i++) s += CR[i]*CR[i];
    NRM[t] = sqrt(s);
  }
  __syncthreads();

  if (t < 363) {
    double alpha = sqrt((double)(2*l3+1) / (double)NOUT3[l3]);
    ws[p*128 + loc] = (float)(CR[t] / NRM[p] * alpha);
  }
}

// ======================================================================
// Main fused kernel: w = dist@W + b (W staged in LDS), then per-item TP
// with CG coefficients via uniform scalar loads from d_ws.
// Block: 256 threads = 32 channels x 8 b-groups; 4 items/thread (R=4);
// block tile = 32 b x 32 c = 1024 items. Grid = B/32 = 4096.
// ======================================================================
template<int L1,int L2,int L3>
__device__ __forceinline__ void tp_path(const float* __restrict__ Cp, float wp,
                                        const float (&xi)[9], const float (&yi)[9],
                                        float (&o)[9])
{
  constexpr int D1 = 2*L1+1, D2 = 2*L2+1, D3 = 2*L3+1;
  constexpr int O1 = L1*L1,  O2 = L2*L2,  O3 = L3*L3;
  float z[D3];
#pragma unroll
  for (int k = 0; k < D3; k++) z[k] = 0.f;
#pragma unroll
  for (int i = 0; i < D1; i++) {
#pragma unroll
    for (int j = 0; j < D2; j++) {
      float tt = xi[O1+i] * yi[O2+j];
#pragma unroll
      for (int k = 0; k < D3; k++)
        z[k] = fmaf(Cp[(i*D2+j)*D3 + k], tt, z[k]);   // uniform -> s_load
    }
  }
#pragma unroll
  for (int k = 0; k < D3; k++) o[O3+k] = fmaf(wp, z[k], o[O3+k]);
}

__global__ __launch_bounds__(256, 3) void e3_tp_kernel(
    const float* __restrict__ x, const float* __restrict__ y,
    const float* __restrict__ dist, const float* __restrict__ Wl,
    const float* __restrict__ bias, const float* __restrict__ cg,
    float* __restrict__ out)
{
  __shared__ vf4 Ws4[32*32*3];           // W as [f][c][12] floats, 48 KB
  float* Ws = (float*)Ws4;
  const int t = threadIdx.x;

  { // stage W_lin [32][352] -> LDS [f][c][12]; thread (a=t>>5, b=t&31)
    const int a = t >> 5, b = t & 31;
    const float* src = Wl + b*11;
    float*       dst = Ws + b*12;
#pragma unroll
    for (int kf = 0; kf < 4; kf++) {
      const int f = a*4 + kf;
#pragma unroll
      for (int p = 0; p < 11; p++)
        dst[f*384 + p] = src[f*352 + p];
    }
  }
  __syncthreads();

  const int c = t & 31, g = t >> 5;
  const long b0 = (long)blockIdx.x*32 + g*4;

  // ---- fused linear: w[r][p] = bias + sum_f dist[b0+r][f] * W[f][c][p] ----
  float w[4][11];
#pragma unroll
  for (int p = 0; p < 11; p++){
    float bb = bias[c*11 + p];
#pragma unroll
    for (int r = 0; r < 4; r++) w[r][p] = bb;
  }

  const float* db = dist + b0*32;
  const vf4* wsrow = Ws4 + c*3;
#pragma unroll 1
  for (int fq = 0; fq < 8; fq++){
    vf4 dd[4];
#pragma unroll
    for (int r = 0; r < 4; r++) dd[r] = *(const vf4*)(db + r*32 + fq*4);
#pragma unroll
    for (int ff = 0; ff < 4; ff++){
      const vf4* wr = wsrow + (fq*4 + ff)*96;
      vf4 wa = wr[0], wb2 = wr[1], wc2 = wr[2];   // 3x ds_read_b128
      const float wl[11] = {wa.x,wa.y,wa.z,wa.w, wb2.x,wb2.y,wb2.z,wb2.w, wc2.x,wc2.y,wc2.z};
#pragma unroll
      for (int r = 0; r < 4; r++){
        const float dv = (ff==0) ? dd[r].x : (ff==1) ? dd[r].y : (ff==2) ? dd[r].z : dd[r].w;
#pragma unroll
        for (int p = 0; p < 11; p++) w[r][p] = fmaf(dv, wl[p], w[r][p]);
      }
    }
  }

  // ---- per-item tensor product ----
  const long ib = b0*32 + c;
  const float* xp = x + ib*9;
  const float* yp = y + ib*9;
  float* op = out + ib*9;

#pragma unroll
  for (int r = 0; r < 4; r++){
    const float* xr = xp + r*288;
    const float* yr = yp + r*288;
    float xi[9], yi[9], o[9];
    { vf4 a_, b_; __builtin_memcpy(&a_, xr, 16); __builtin_memcpy(&b_, xr+4, 16);
      xi[0]=a_.x; xi[1]=a_.y; xi[2]=a_.z; xi[3]=a_.w;
      xi[4]=b_.x; xi[5]=b_.y; xi[6]=b_.z; xi[7]=b_.w; xi[8]=xr[8]; }
    { vf4 a_, b_; __builtin_memcpy(&a_, yr, 16); __builtin_memcpy(&b_, yr+4, 16);
      yi[0]=a_.x; yi[1]=a_.y; yi[2]=a_.z; yi[3]=a_.w;
      yi[4]=b_.x; yi[5]=b_.y; yi[6]=b_.z; yi[7]=b_.w; yi[8]=yr[8]; }
#pragma unroll
    for (int k = 0; k < 9; k++) o[k] = 0.f;

    tp_path<0,0,0>(cg + 0*128,  w[r][0],  xi, yi, o);
    tp_path<0,1,1>(cg + 1*128,  w[r][1],  xi, yi, o);
    tp_path<0,2,2>(cg + 2*128,  w[r][2],  xi, yi, o);
    tp_path<1,0,1>(cg + 3*128,  w[r][3],  xi, yi, o);
    tp_path<1,1,0>(cg + 4*128,  w[r][4],  xi, yi, o);
    tp_path<1,1,2>(cg + 5*128,  w[r][5],  xi, yi, o);
    tp_path<1,2,1>(cg + 6*128,  w[r][6],  xi, yi, o);
    tp_path<2,0,2>(cg + 7*128,  w[r][7],  xi, yi, o);
    tp_path<2,1,1>(cg + 8*128,  w[r][8],  xi, yi, o);
    tp_path<2,2,0>(cg + 9*128,  w[r][9],  xi, yi, o);
    tp_path<2,2,2>(cg + 10*128, w[r][10], xi, yi, o);

    float* o0 = op + r*288;
    vf4 s0 = { o[0], o[1], o[2], o[3] };
    vf4 s1 = { o[4], o[5], o[6], o[7] };
    __builtin_memcpy(o0,     &s0, 16);
    __builtin_memcpy(o0 + 4, &s1, 16);
    o0[8] = o[8];
  }
}

extern "C" void kernel_launch(void* const* d_in, const int* in_sizes, int n_in,
                              void* d_out, int out_size, void* d_ws, size_t ws_size,
                              hipStream_t stream)
{
  const float* x    = (const float*)d_in[0];
  const float* y    = (const float*)d_in[1];
  const float* dist = (const float*)d_in[2];
  const float* Wl   = (const float*)d_in[3];
  const float* bl   = (const float*)d_in[4];
  float* out = (float*)d_out;
  float* ws  = (float*)d_ws;

  hipLaunchKernelGGL(cg_setup_kernel, dim3(1), dim3(512), 0, stream, ws);

  const int B = in_sizes[2] / 32;        // 131072 rows
  const int nblocks = B / 32;            // 32 b's per block
  hipLaunchKernelGGL(e3_tp_kernel, dim3(nblocks), dim3(256), 0, stream,
                     x, y, dist, Wl, bl, ws, out);
}